// Round 12
// baseline (173.847 us; speedup 1.0000x reference)
//
#include <hip/hip_runtime.h>
#include <hip/hip_bf16.h>
#include <cmath>
#include <stdint.h>

// B=2, T=2048, D_MODEL=1024, H=16, KVH=4, HEAD_DIM=64, NUM_REP=4. Causal.
// GEMM A operands: bf16 pre-tiled [tile(128m x 64k)] -> [kb][m][8] (8192/tile)
// GEMM B operands: bf16 pre-tiled [tile(64n x 64k)]  -> [kb][n][8] (4096/tile)
// Flash K/V: per-64-key-chunk fragment-tiled [chunk][kb][row][8] (4096/chunk),
// K additionally KEY-PERMUTED by pi (swap 4-groups [4..7]<->[8..11] mod 16,
// self-inverse) so the 32x32 S^T C-layout scramble cancels: each lane's C regs
// hold exactly the PV A-fragment slots it needs, in order -> no cross-lane
// shuffle for P. V needs no permutation (A-slot k carries logical key k).

typedef __attribute__((ext_vector_type(4))) float f32x4;
typedef __attribute__((ext_vector_type(16))) float f32x16;
typedef __attribute__((ext_vector_type(8))) short s16x8;
typedef __attribute__((ext_vector_type(8))) unsigned short u16x8;

#define MFMA32(a, b, c) __builtin_amdgcn_mfma_f32_32x32x16_bf16(a, b, c, 0, 0, 0)

__device__ __forceinline__ unsigned short f2bf(float f) {
    unsigned int u = __float_as_uint(f);
    u += 0x7FFFu + ((u >> 16) & 1u);   // round-to-nearest-even
    return (unsigned short)(u >> 16);
}

// pack two f32 -> bf16x2 by truncation: one v_perm_b32
__device__ __forceinline__ unsigned int pktr(float lo, float hi) {
    return __builtin_amdgcn_perm(__float_as_uint(hi), __float_as_uint(lo), 0x07060302u);
}

__device__ __forceinline__ void async16(void* lds, const void* g) {
    __builtin_amdgcn_global_load_lds(
        (const __attribute__((address_space(1))) unsigned int*)g,
        (__attribute__((address_space(3))) unsigned int*)lds, 16, 0, 0);
}

// ---- fused preprocessing ---------------------------------------------------
__global__ __launch_bounds__(256) void prep(
        const float* __restrict__ x,
        const float* __restrict__ Wq, const float* __restrict__ Wk,
        const float* __restrict__ Wv, const float* __restrict__ Wo,
        const float* __restrict__ bq, const float* __restrict__ bk,
        const float* __restrict__ bv,
        unsigned short* __restrict__ xb, unsigned short* __restrict__ Wqkv,
        unsigned short* __restrict__ Wot, float* __restrict__ biasq, float qscale) {
    __shared__ unsigned short sx[128 * 72];
    __shared__ float tile[32][33];
    const int bid = blockIdx.x, tid = threadIdx.x;
    if (bid < 512) {                        // x panel: 128m x 64k, LDS bounce
        const int mt = bid >> 4, kt = bid & 15;
#pragma unroll
        for (int i = 0; i < 8; ++i) {
            const int flat = (i * 256 + tid) * 4;
            const int row = flat >> 6, col = flat & 63;
            f32x4 ld = *reinterpret_cast<const f32x4*>(
                &x[(size_t)(mt * 128 + row) * 1024 + kt * 64 + col]);
            unsigned short* d = &sx[row * 72 + col];
            d[0] = f2bf(ld.x); d[1] = f2bf(ld.y); d[2] = f2bf(ld.z); d[3] = f2bf(ld.w);
        }
        __syncthreads();
#pragma unroll
        for (int j = 0; j < 4; ++j) {
            const int idx = j * 256 + tid;
            const int kb = idx >> 7, m = idx & 127;
            u16x8 v = *reinterpret_cast<const u16x8*>(&sx[m * 72 + kb * 8]);
            *reinterpret_cast<u16x8*>(
                &xb[(size_t)(((mt * 16 + kt) * 8 + kb) * 128 + m) * 8]) = v;
        }
    } else if (bid < 3072) {                // weight transpose -> B-tiled W^T
        int id = bid - 512;
        const float* W; unsigned short* out; int N, nbase; float scale = 1.0f;
        if (id < 1024)      { W = Wq; out = Wqkv; N = 1024; nbase = 0;    scale = qscale; }
        else if (id < 1280) { W = Wk; out = Wqkv; N = 256;  nbase = 1024; id -= 1024; }
        else if (id < 1536) { W = Wv; out = Wqkv; N = 256;  nbase = 1280; id -= 1280; }
        else                { W = Wo; out = Wot;  N = 1024; nbase = 0;    id -= 1536; }
        const int nb = N >> 5;
        const int n0 = (id % nb) * 32, k0 = (id / nb) * 32;
        const int tx = tid & 31, ty = tid >> 5;
#pragma unroll
        for (int r = 0; r < 4; ++r)
            tile[ty + r * 8][tx] = W[(size_t)(k0 + ty + r * 8) * N + n0 + tx];
        __syncthreads();
        const int k = k0 + tx;
#pragma unroll
        for (int r = 0; r < 4; ++r) {
            const int n = nbase + n0 + ty + r * 8;
            size_t addr = (size_t)((n >> 6) * 16 + (k >> 6)) * 4096
                        + (size_t)((((k >> 3) & 7) * 64 + (n & 63)) * 8 + (k & 7));
            out[addr] = f2bf(tile[tx][ty + r * 8] * scale);
        }
    } else {                                // bias concat
        const int i = (bid - 3072) * 256 + tid;
        if (i < 1024) biasq[i] = bq[i] * qscale;
        else if (i < 1280) biasq[i] = bk[i - 1024];
        else biasq[i] = bv[i - 1280];
    }
}

// ---- 128x64-tile MFMA32 GEMM, K=1024, double-buffered global_load_lds ------
// EPI 0: QKV split. Q bf16 [row][1024] prescaled.
//        K -> chunk-tiled Ktl[(b*4+kvh)*32+c][kb_d][pi(s)][8d]  (key-permuted)
//        V -> chunk-tiled Vtl[(b*4+kvh)*32+c][kb_s][d][8s]      (unpermuted)
// EPI 1: f32 [row][1024].
template <int EPI>
__global__ __launch_bounds__(256) void gemm_mn(
        const unsigned short* __restrict__ A, const unsigned short* __restrict__ Bt,
        const float* __restrict__ bias,
        unsigned short* __restrict__ oQ, unsigned short* __restrict__ oK,
        unsigned short* __restrict__ oV, float* __restrict__ oF) {
    __shared__ alignas(16) unsigned short smem[24576];  // 48 KB: A dbuf 2x16KB, B dbuf 2x8KB
    const int tid = threadIdx.x;
    const int lane = tid & 63, w = tid >> 6;
    const int l31 = lane & 31, grp = lane >> 5;
    const int m0 = blockIdx.y * 128, n0 = blockIdx.x * 64;
    const int wm = w * 32;

    const unsigned short* Abase = A + (size_t)blockIdx.y * (16 * 8192) + (size_t)tid * 8;
    const unsigned short* Bbase = Bt + (size_t)blockIdx.x * (16 * 4096) + (size_t)tid * 8;

    f32x16 acc0 = {}, acc1 = {};

    // preload kt=0 into buf 0
#pragma unroll
    for (int i = 0; i < 4; ++i)
        async16(&smem[(size_t)(i * 256 + (tid & 192)) * 8], Abase + (size_t)i * 2048);
#pragma unroll
    for (int i = 0; i < 2; ++i)
        async16(&smem[16384 + (size_t)(i * 256 + (tid & 192)) * 8], Bbase + (size_t)i * 2048);

    for (int kt = 0; kt < 16; ++kt) {
        const int cur = kt & 1;
        unsigned short* cA = smem + cur * 8192;
        unsigned short* cB = smem + 16384 + cur * 4096;
        __syncthreads();                      // buf[cur] landed; buf[cur^1] readers done
        if (kt < 15) {                        // stage kt+1 under compute
            unsigned short* nA = smem + (cur ^ 1) * 8192;
            unsigned short* nB = smem + 16384 + (cur ^ 1) * 4096;
            const unsigned short* ab = Abase + (size_t)(kt + 1) * 8192;
            const unsigned short* bb = Bbase + (size_t)(kt + 1) * 4096;
#pragma unroll
            for (int i = 0; i < 4; ++i)
                async16(&nA[(size_t)(i * 256 + (tid & 192)) * 8], ab + (size_t)i * 2048);
#pragma unroll
            for (int i = 0; i < 2; ++i)
                async16(&nB[(size_t)(i * 256 + (tid & 192)) * 8], bb + (size_t)i * 2048);
        }
#pragma unroll
        for (int kc = 0; kc < 4; ++kc) {
            const int kb = kc * 2 + grp;      // frag k = kc*16 + grp*8 + j
            s16x8 a  = *reinterpret_cast<const s16x8*>(&cA[(size_t)(kb * 128 + wm + l31) * 8]);
            s16x8 b0 = *reinterpret_cast<const s16x8*>(&cB[(size_t)(kb * 64 + l31) * 8]);
            s16x8 b1 = *reinterpret_cast<const s16x8*>(&cB[(size_t)(kb * 64 + 32 + l31) * 8]);
            acc0 = MFMA32(a, b0, acc0);
            acc1 = MFMA32(a, b1, acc1);
        }
    }
    const float bv0 = bias[n0 + l31], bv1 = bias[n0 + 32 + l31];
    if (EPI == 0 && n0 >= 1280) {   // V -> chunk-tiled V^T via LDS bounce
        __syncthreads();            // all frag reads done; smem reusable
        const int kvh = (n0 - 1280) >> 6;
#pragma unroll
        for (int r = 0; r < 16; ++r) {
            const int m = wm + (r & 3) + 8 * (r >> 2) + 4 * grp;   // local s, 0..127
            smem[(size_t)l31 * 136 + m] = f2bf(acc0[r] + bv0);     // [d][s]
            smem[(size_t)(l31 + 32) * 136 + m] = f2bf(acc1[r] + bv1);
        }
        __syncthreads();
        const int b = m0 >> 11, c0 = (m0 & 2047) >> 6;
        unsigned short* vb = oV + (size_t)((b * 4 + kvh) * 32 + c0) * 4096;
#pragma unroll
        for (int i = 0; i < 4; ++i) {
            const int id = i * 256 + tid;          // 1024 x 16B chunks
            const int d = id >> 4, mc = id & 15;   // 8 consecutive s each
            u16x8 v = *reinterpret_cast<const u16x8*>(&smem[(size_t)d * 136 + mc * 8]);
            *reinterpret_cast<u16x8*>(&vb[(size_t)(mc >> 3) * 4096
                + ((size_t)(mc & 7) * 64 + d) * 8]) = v;
        }
        return;
    }
    if (EPI == 0 && n0 >= 1024) {   // K -> chunk-tiled + key-permuted (pi)
        __syncthreads();
        const int kvh = (n0 - 1024) >> 6;
#pragma unroll
        for (int r = 0; r < 16; ++r) {
            const int m = wm + (r & 3) + 8 * (r >> 2) + 4 * grp;   // local s, 0..127
            smem[(size_t)m * 72 + l31] = f2bf(acc0[r] + bv0);      // [s][d]
            smem[(size_t)m * 72 + 32 + l31] = f2bf(acc1[r] + bv1);
        }
        __syncthreads();
        const int b = m0 >> 11, c0 = (m0 & 2047) >> 6;
        unsigned short* kb_o = oK + (size_t)((b * 4 + kvh) * 32 + c0) * 4096;
#pragma unroll
        for (int i = 0; i < 4; ++i) {
            const int id = i * 256 + tid;          // 1024 x 16B chunks
            const int si = id >> 3, dc = id & 7;   // si 0..127, 8 consecutive d
            const int s6 = si & 63;
            const int g2 = (s6 >> 2) & 3;          // pi: swap 4-groups 1<->2 mod 16
            const int sp = (g2 == 1 || g2 == 2) ? (s6 ^ 12) : s6;
            u16x8 v = *reinterpret_cast<const u16x8*>(&smem[(size_t)si * 72 + dc * 8]);
            *reinterpret_cast<u16x8*>(&kb_o[(size_t)(si >> 6) * 4096
                + ((size_t)dc * 64 + sp) * 8]) = v;
        }
        return;
    }
#pragma unroll
    for (int r = 0; r < 16; ++r) {
        const int row = m0 + wm + (r & 3) + 8 * (r >> 2) + 4 * grp;
        const float v0 = acc0[r] + bv0, v1 = acc1[r] + bv1;
        if (EPI == 0) {             // Q (block-uniform)
            oQ[(size_t)row * 1024 + n0 + l31] = f2bf(v0);
            oQ[(size_t)row * 1024 + n0 + 32 + l31] = f2bf(v1);
        } else {
            oF[(size_t)row * 1024 + n0 + l31] = v0;
            oF[(size_t)row * 1024 + n0 + 32 + l31] = v1;
        }
    }
}

// ---- MFMA flash attention: barrier-free chunk loop, 4-wave key split, ------
// key-permuted K so P A-frags are straight in-lane packs (no shuffles).
// Block = 256 threads = 4 waves on the SAME 32-row q-strip of one (b,h);
// wave w does chunks c = w, w+4, ... (exp2-domain softmax: partials over
// disjoint chunk sets are additive -- validated R2-R11). The 4-way split
// halves the heaviest serial tail (strip 63: 16 -> 8 chunks/wave). One final
// __syncthreads; waves 1-3 park partials in LDS, wave 0 combines.
// With pi-permuted K, S^T C reg r at grp g = logical key
// s0 + ((r&8)<<1) + 8g + (r&7)  (st1: +32), and A-frag for PV segment kkp is
// pack(regs 8*(kkp&1) .. +7) of p0 (kkp<2) or p1 -- in-register, in-order.
// Qb bf16 [b*2048+t][h*64+d] pre-scaled by 0.125*log2e.
// O stored bf16 in GEMM A-tiled layout for the O-projection.
__global__ __launch_bounds__(256) void flash_attn(
        const unsigned short* __restrict__ Qb, const unsigned short* __restrict__ Ktl,
        const unsigned short* __restrict__ Vtl, unsigned short* __restrict__ Ot) {
    __shared__ float sO[3][64][33];             // waves 1-3 partial O (stride 33: conflict-free)
    __shared__ float sL[3][64];                 // waves 1-3 partial l
    const int tid = threadIdx.x;
    const int lane = tid & 63, w = tid >> 6;    // w: 0..3 (key-split)
    const int ln = lane & 31, grp = lane >> 5;
    const int id = blockIdx.x;                  // 0..2047
    const int kvh = id & 3;
    const int b = (id >> 2) & 1;
    const int h = kvh * 4 + ((id >> 3) & 3);
    const int strip = 63 - (id >> 5);           // heavy strips first
    const int t0w = strip * 32;
    const int qrow_g = t0w + ln;
    const int nch = (strip >> 1) + 1;           // causal 64-key chunks

    // Q B-frags in registers (read once): qf[kk] holds d = kk*16 + grp*8 + j
    const unsigned short* Qrow = Qb + (size_t)(b * 2048 + qrow_g) * 1024 + h * 64;
    s16x8 qf[4];
#pragma unroll
    for (int kk = 0; kk < 4; ++kk)
        qf[kk] = *reinterpret_cast<const s16x8*>(Qrow + kk * 16 + grp * 8);

    // per-(b,kvh) chunk-tiled bases; lane offset (grp*64+ln)*8 within a frag row
    const unsigned short* Kc = Ktl + (size_t)((b * 4 + kvh) * 32) * 4096
                                   + ((size_t)grp * 64 + ln) * 8;
    const unsigned short* Vc = Vtl + (size_t)((b * 4 + kvh) * 32) * 4096
                                   + ((size_t)grp * 64 + ln) * 8;

    f32x16 o0 = {}, o1 = {};
    float ltot = 0.f;

    for (int c = w; c < nch; c += 4) {          // barrier-free, 4-way interleave
        const int s0 = c * 64;
        const unsigned short* kc = Kc + (size_t)c * 4096;
        const unsigned short* vc = Vc + (size_t)c * 4096;
        // ---- coalesced K/V fragment loads (K first: V stays in flight) ----
        s16x8 kf0[4], kf1[4], vf0[4], vf1[4];
#pragma unroll
        for (int kk = 0; kk < 4; ++kk) {
            kf0[kk] = *reinterpret_cast<const s16x8*>(kc + kk * 1024);
            kf1[kk] = *reinterpret_cast<const s16x8*>(kc + kk * 1024 + 256);
        }
#pragma unroll
        for (int kk = 0; kk < 4; ++kk) {
            vf0[kk] = *reinterpret_cast<const s16x8*>(vc + kk * 1024);
            vf1[kk] = *reinterpret_cast<const s16x8*>(vc + kk * 1024 + 256);
        }
        // ---- S^T = K Q^T : C[row=permuted key][col=qrow] ----
        f32x16 st0 = {}, st1 = {};
#pragma unroll
        for (int kk = 0; kk < 4; ++kk) {
            st0 = MFMA32(kf0[kk], qf[kk], st0);
            st1 = MFMA32(kf1[kk], qf[kk], st1);
        }
        if (s0 + 63 > t0w) {                   // diagonal chunk: causal mask (logical keys)
#pragma unroll
            for (int r = 0; r < 16; ++r) {
                const int keyo = s0 + ((r & 8) << 1) + 8 * grp + (r & 7);
                if (keyo > qrow_g)      st0[r] = -INFINITY;
                if (keyo + 32 > qrow_g) st1[r] = -INFINITY;
            }
        }
        // ---- P = exp2(S^T); all 32 values belong to qrow = ln ----
        f32x16 p0, p1;
#pragma unroll
        for (int r = 0; r < 16; ++r) {
            p0[r] = __builtin_amdgcn_exp2f(st0[r]);
            p1[r] = __builtin_amdgcn_exp2f(st1[r]);
        }
        float a0 = 0.f, a1 = 0.f, a2 = 0.f, a3 = 0.f;
#pragma unroll
        for (int r = 0; r < 16; r += 2) {
            a0 += p0[r]; a1 += p0[r + 1];
            a2 += p1[r]; a3 += p1[r + 1];
        }
        ltot += (a0 + a1) + (a2 + a3);
        // ---- P A-frags: straight in-lane packs (pi cancels the C scramble) ----
#pragma unroll
        for (int kkp = 0; kkp < 4; ++kkp) {
            const f32x16& pm = (kkp < 2) ? p0 : p1;
            const int base = 8 * (kkp & 1);
            union { unsigned int u[4]; s16x8 v; } pf;
            pf.u[0] = pktr(pm[base + 0], pm[base + 1]);
            pf.u[1] = pktr(pm[base + 2], pm[base + 3]);
            pf.u[2] = pktr(pm[base + 4], pm[base + 5]);
            pf.u[3] = pktr(pm[base + 6], pm[base + 7]);
            o0 = MFMA32(pf.v, vf0[kkp], o0);
            o1 = MFMA32(pf.v, vf1[kkp], o1);
        }
    }

    // ---- combine waves 1-3 partials into wave 0 (single barrier) ----
    if (w) {
#pragma unroll
        for (int r = 0; r < 16; ++r) {
            sO[w - 1][lane][r] = o0[r];
            sO[w - 1][lane][16 + r] = o1[r];
        }
        sL[w - 1][lane] = ltot;
    }
    __syncthreads();
    if (w) return;
#pragma unroll
    for (int j = 0; j < 3; ++j) {
#pragma unroll
        for (int r = 0; r < 16; ++r) {
            o0[r] += sO[j][lane][r];
            o1[r] += sO[j][lane][16 + r];
        }
        ltot += sL[j][lane];
    }

    // ---- normalize + store bf16 in GEMM A-tiled layout ----
    const float lfull = ltot + __shfl_xor(ltot, 32, 64);
    const float rl = 1.0f / lfull;             // valid at every lane for row=ln
    unsigned short* Otb = Ot + (size_t)((b * 16 + (strip >> 2)) * 16 + h) * 8192
                             + (size_t)(ln >> 3) * 1024 + (ln & 7);
#pragma unroll
    for (int r = 0; r < 16; ++r) {
        const int row = (r & 3) + 8 * (r >> 2) + 4 * grp;
        const float rr = __shfl(rl, row, 64);
        const size_t off = (size_t)((strip & 3) * 32 + row) * 8;
        Otb[off]        = f2bf(o0[r] * rr);    // d-tile 0 (cols h*64+0..31)
        Otb[off + 4096] = f2bf(o1[r] * rr);    // d-tile 1 (cols h*64+32..63)
    }
}

// ---------------------------------------------------------------------------
extern "C" void kernel_launch(void* const* d_in, const int* in_sizes, int n_in,
                              void* d_out, int out_size, void* d_ws, size_t ws_size,
                              hipStream_t stream) {
    const float* x  = (const float*)d_in[0];
    // d_in[1] = causal mask, analytic -> ignored
    const float* Wq = (const float*)d_in[2];
    const float* bq = (const float*)d_in[3];
    const float* Wk = (const float*)d_in[4];
    const float* bk = (const float*)d_in[5];
    const float* Wv = (const float*)d_in[6];
    const float* bv = (const float*)d_in[7];
    const float* Wo = (const float*)d_in[8];
    const float* bo = (const float*)d_in[9];
    float* out = (float*)d_out;

    char* ws = (char*)d_ws;
    unsigned short* xb    = (unsigned short*)(ws);                  // 8 MB  A-tiled bf16 x
    unsigned short* Wqkv  = (unsigned short*)(ws + (8u  << 20));    // 3 MB  B-tiled concat W^T
    unsigned short* Wot   = (unsigned short*)(ws + (12u << 20));    // 2 MB  B-tiled Wo^T
    float*          biasq = (float*)         (ws + (15u << 20));    // 6 KB
    unsigned short* Qb    = (unsigned short*)(ws + (16u << 20));    // 8 MB
    unsigned short* Ktl   = (unsigned short*)(ws + (24u << 20));    // 2 MB chunk-tiled K (pi-permuted)
    unsigned short* Vtl   = (unsigned short*)(ws + (26u << 20));    // 2 MB chunk-tiled V^T
    unsigned short* Otl   = (unsigned short*)(ws + (28u << 20));    // 8 MB A-tiled (ends 36 MB)

    const float qscale = 0.125f * 1.4426950408889634f;  // 1/sqrt(64) * log2(e)

    prep<<<3078, 256, 0, stream>>>(x, Wq, Wk, Wv, Wo, bq, bk, bv,
                                   xb, Wqkv, Wot, biasq, qscale);
    gemm_mn<0><<<dim3(24, 32), 256, 0, stream>>>(xb, Wqkv, biasq, Qb, Ktl, Vtl, nullptr);
    flash_attn<<<2048, 256, 0, stream>>>(Qb, Ktl, Vtl, Otl);
    gemm_mn<1><<<dim3(16, 32), 256, 0, stream>>>(Otl, Wot, bo, nullptr, nullptr, nullptr, out);
}

// Round 13
// 158.511 us; speedup vs baseline: 1.0968x; 1.0968x over previous
//
#include <hip/hip_runtime.h>
#include <hip/hip_bf16.h>
#include <cmath>
#include <stdint.h>

// B=2, T=2048, D_MODEL=1024, H=16, KVH=4, HEAD_DIM=64, NUM_REP=4. Causal.
// GEMM A operands: bf16 pre-tiled [tile(128m x 64k)] -> [kb][m][8] (8192/tile)
// GEMM B operands: bf16 pre-tiled [tile(64n x 64k)]  -> [kb][n][8] (4096/tile)
// Flash K/V: per-64-key-chunk fragment-tiled [chunk][kb][row][8] (4096/chunk),
// K additionally KEY-PERMUTED by pi (swap 4-groups [4..7]<->[8..11] mod 16,
// self-inverse) so the 32x32 S^T C-layout scramble cancels: each lane's C regs
// hold exactly the PV A-fragment slots it needs, in order -> no cross-lane
// shuffle for P. V needs no permutation (A-slot k carries logical key k).
// Validated R12 (absmax unchanged).

typedef __attribute__((ext_vector_type(4))) float f32x4;
typedef __attribute__((ext_vector_type(16))) float f32x16;
typedef __attribute__((ext_vector_type(8))) short s16x8;
typedef __attribute__((ext_vector_type(8))) unsigned short u16x8;

#define MFMA32(a, b, c) __builtin_amdgcn_mfma_f32_32x32x16_bf16(a, b, c, 0, 0, 0)

__device__ __forceinline__ unsigned short f2bf(float f) {
    unsigned int u = __float_as_uint(f);
    u += 0x7FFFu + ((u >> 16) & 1u);   // round-to-nearest-even
    return (unsigned short)(u >> 16);
}

// pack two f32 -> bf16x2 by truncation: one v_perm_b32
__device__ __forceinline__ unsigned int pktr(float lo, float hi) {
    return __builtin_amdgcn_perm(__float_as_uint(hi), __float_as_uint(lo), 0x07060302u);
}

__device__ __forceinline__ void async16(void* lds, const void* g) {
    __builtin_amdgcn_global_load_lds(
        (const __attribute__((address_space(1))) unsigned int*)g,
        (__attribute__((address_space(3))) unsigned int*)lds, 16, 0, 0);
}

// ---- fused preprocessing ---------------------------------------------------
__global__ __launch_bounds__(256) void prep(
        const float* __restrict__ x,
        const float* __restrict__ Wq, const float* __restrict__ Wk,
        const float* __restrict__ Wv, const float* __restrict__ Wo,
        const float* __restrict__ bq, const float* __restrict__ bk,
        const float* __restrict__ bv,
        unsigned short* __restrict__ xb, unsigned short* __restrict__ Wqkv,
        unsigned short* __restrict__ Wot, float* __restrict__ biasq, float qscale) {
    __shared__ unsigned short sx[128 * 72];
    __shared__ float tile[32][33];
    const int bid = blockIdx.x, tid = threadIdx.x;
    if (bid < 512) {                        // x panel: 128m x 64k, LDS bounce
        const int mt = bid >> 4, kt = bid & 15;
#pragma unroll
        for (int i = 0; i < 8; ++i) {
            const int flat = (i * 256 + tid) * 4;
            const int row = flat >> 6, col = flat & 63;
            f32x4 ld = *reinterpret_cast<const f32x4*>(
                &x[(size_t)(mt * 128 + row) * 1024 + kt * 64 + col]);
            unsigned short* d = &sx[row * 72 + col];
            d[0] = f2bf(ld.x); d[1] = f2bf(ld.y); d[2] = f2bf(ld.z); d[3] = f2bf(ld.w);
        }
        __syncthreads();
#pragma unroll
        for (int j = 0; j < 4; ++j) {
            const int idx = j * 256 + tid;
            const int kb = idx >> 7, m = idx & 127;
            u16x8 v = *reinterpret_cast<const u16x8*>(&sx[m * 72 + kb * 8]);
            *reinterpret_cast<u16x8*>(
                &xb[(size_t)(((mt * 16 + kt) * 8 + kb) * 128 + m) * 8]) = v;
        }
    } else if (bid < 3072) {                // weight transpose -> B-tiled W^T
        int id = bid - 512;
        const float* W; unsigned short* out; int N, nbase; float scale = 1.0f;
        if (id < 1024)      { W = Wq; out = Wqkv; N = 1024; nbase = 0;    scale = qscale; }
        else if (id < 1280) { W = Wk; out = Wqkv; N = 256;  nbase = 1024; id -= 1024; }
        else if (id < 1536) { W = Wv; out = Wqkv; N = 256;  nbase = 1280; id -= 1280; }
        else                { W = Wo; out = Wot;  N = 1024; nbase = 0;    id -= 1536; }
        const int nb = N >> 5;
        const int n0 = (id % nb) * 32, k0 = (id / nb) * 32;
        const int tx = tid & 31, ty = tid >> 5;
#pragma unroll
        for (int r = 0; r < 4; ++r)
            tile[ty + r * 8][tx] = W[(size_t)(k0 + ty + r * 8) * N + n0 + tx];
        __syncthreads();
        const int k = k0 + tx;
#pragma unroll
        for (int r = 0; r < 4; ++r) {
            const int n = nbase + n0 + ty + r * 8;
            size_t addr = (size_t)((n >> 6) * 16 + (k >> 6)) * 4096
                        + (size_t)((((k >> 3) & 7) * 64 + (n & 63)) * 8 + (k & 7));
            out[addr] = f2bf(tile[tx][ty + r * 8] * scale);
        }
    } else {                                // bias concat
        const int i = (bid - 3072) * 256 + tid;
        if (i < 1024) biasq[i] = bq[i] * qscale;
        else if (i < 1280) biasq[i] = bk[i - 1024];
        else biasq[i] = bv[i - 1280];
    }
}

// ---- 128x64-tile MFMA32 GEMM, K=1024, double-buffered global_load_lds ------
// EPI 0: QKV split. Q bf16 [row][1024] prescaled.
//        K -> chunk-tiled Ktl[(b*4+kvh)*32+c][kb_d][pi(s)][8d]  (key-permuted)
//        V -> chunk-tiled Vtl[(b*4+kvh)*32+c][kb_s][d][8s]      (unpermuted)
// EPI 1: f32 [row][1024].
template <int EPI>
__global__ __launch_bounds__(256) void gemm_mn(
        const unsigned short* __restrict__ A, const unsigned short* __restrict__ Bt,
        const float* __restrict__ bias,
        unsigned short* __restrict__ oQ, unsigned short* __restrict__ oK,
        unsigned short* __restrict__ oV, float* __restrict__ oF) {
    __shared__ alignas(16) unsigned short smem[24576];  // 48 KB: A dbuf 2x16KB, B dbuf 2x8KB
    const int tid = threadIdx.x;
    const int lane = tid & 63, w = tid >> 6;
    const int l31 = lane & 31, grp = lane >> 5;
    const int m0 = blockIdx.y * 128, n0 = blockIdx.x * 64;
    const int wm = w * 32;

    const unsigned short* Abase = A + (size_t)blockIdx.y * (16 * 8192) + (size_t)tid * 8;
    const unsigned short* Bbase = Bt + (size_t)blockIdx.x * (16 * 4096) + (size_t)tid * 8;

    f32x16 acc0 = {}, acc1 = {};

    // preload kt=0 into buf 0
#pragma unroll
    for (int i = 0; i < 4; ++i)
        async16(&smem[(size_t)(i * 256 + (tid & 192)) * 8], Abase + (size_t)i * 2048);
#pragma unroll
    for (int i = 0; i < 2; ++i)
        async16(&smem[16384 + (size_t)(i * 256 + (tid & 192)) * 8], Bbase + (size_t)i * 2048);

    for (int kt = 0; kt < 16; ++kt) {
        const int cur = kt & 1;
        unsigned short* cA = smem + cur * 8192;
        unsigned short* cB = smem + 16384 + cur * 4096;
        __syncthreads();                      // buf[cur] landed; buf[cur^1] readers done
        if (kt < 15) {                        // stage kt+1 under compute
            unsigned short* nA = smem + (cur ^ 1) * 8192;
            unsigned short* nB = smem + 16384 + (cur ^ 1) * 4096;
            const unsigned short* ab = Abase + (size_t)(kt + 1) * 8192;
            const unsigned short* bb = Bbase + (size_t)(kt + 1) * 4096;
#pragma unroll
            for (int i = 0; i < 4; ++i)
                async16(&nA[(size_t)(i * 256 + (tid & 192)) * 8], ab + (size_t)i * 2048);
#pragma unroll
            for (int i = 0; i < 2; ++i)
                async16(&nB[(size_t)(i * 256 + (tid & 192)) * 8], bb + (size_t)i * 2048);
        }
#pragma unroll
        for (int kc = 0; kc < 4; ++kc) {
            const int kb = kc * 2 + grp;      // frag k = kc*16 + grp*8 + j
            s16x8 a  = *reinterpret_cast<const s16x8*>(&cA[(size_t)(kb * 128 + wm + l31) * 8]);
            s16x8 b0 = *reinterpret_cast<const s16x8*>(&cB[(size_t)(kb * 64 + l31) * 8]);
            s16x8 b1 = *reinterpret_cast<const s16x8*>(&cB[(size_t)(kb * 64 + 32 + l31) * 8]);
            acc0 = MFMA32(a, b0, acc0);
            acc1 = MFMA32(a, b1, acc1);
        }
    }
    const float bv0 = bias[n0 + l31], bv1 = bias[n0 + 32 + l31];
    if (EPI == 0 && n0 >= 1280) {   // V -> chunk-tiled V^T via LDS bounce
        __syncthreads();            // all frag reads done; smem reusable
        const int kvh = (n0 - 1280) >> 6;
#pragma unroll
        for (int r = 0; r < 16; ++r) {
            const int m = wm + (r & 3) + 8 * (r >> 2) + 4 * grp;   // local s, 0..127
            smem[(size_t)l31 * 136 + m] = f2bf(acc0[r] + bv0);     // [d][s]
            smem[(size_t)(l31 + 32) * 136 + m] = f2bf(acc1[r] + bv1);
        }
        __syncthreads();
        const int b = m0 >> 11, c0 = (m0 & 2047) >> 6;
        unsigned short* vb = oV + (size_t)((b * 4 + kvh) * 32 + c0) * 4096;
#pragma unroll
        for (int i = 0; i < 4; ++i) {
            const int id = i * 256 + tid;          // 1024 x 16B chunks
            const int d = id >> 4, mc = id & 15;   // 8 consecutive s each
            u16x8 v = *reinterpret_cast<const u16x8*>(&smem[(size_t)d * 136 + mc * 8]);
            *reinterpret_cast<u16x8*>(&vb[(size_t)(mc >> 3) * 4096
                + ((size_t)(mc & 7) * 64 + d) * 8]) = v;
        }
        return;
    }
    if (EPI == 0 && n0 >= 1024) {   // K -> chunk-tiled + key-permuted (pi)
        __syncthreads();
        const int kvh = (n0 - 1024) >> 6;
#pragma unroll
        for (int r = 0; r < 16; ++r) {
            const int m = wm + (r & 3) + 8 * (r >> 2) + 4 * grp;   // local s, 0..127
            smem[(size_t)m * 72 + l31] = f2bf(acc0[r] + bv0);      // [s][d]
            smem[(size_t)m * 72 + 32 + l31] = f2bf(acc1[r] + bv1);
        }
        __syncthreads();
        const int b = m0 >> 11, c0 = (m0 & 2047) >> 6;
        unsigned short* kb_o = oK + (size_t)((b * 4 + kvh) * 32 + c0) * 4096;
#pragma unroll
        for (int i = 0; i < 4; ++i) {
            const int id = i * 256 + tid;          // 1024 x 16B chunks
            const int si = id >> 3, dc = id & 7;   // si 0..127, 8 consecutive d
            const int s6 = si & 63;
            const int g2 = (s6 >> 2) & 3;          // pi: swap 4-groups 1<->2 mod 16
            const int sp = (g2 == 1 || g2 == 2) ? (s6 ^ 12) : s6;
            u16x8 v = *reinterpret_cast<const u16x8*>(&smem[(size_t)si * 72 + dc * 8]);
            *reinterpret_cast<u16x8*>(&kb_o[(size_t)(si >> 6) * 4096
                + ((size_t)dc * 64 + sp) * 8]) = v;
        }
        return;
    }
#pragma unroll
    for (int r = 0; r < 16; ++r) {
        const int row = m0 + wm + (r & 3) + 8 * (r >> 2) + 4 * grp;
        const float v0 = acc0[r] + bv0, v1 = acc1[r] + bv1;
        if (EPI == 0) {             // Q (block-uniform)
            oQ[(size_t)row * 1024 + n0 + l31] = f2bf(v0);
            oQ[(size_t)row * 1024 + n0 + 32 + l31] = f2bf(v1);
        } else {
            oF[(size_t)row * 1024 + n0 + l31] = v0;
            oF[(size_t)row * 1024 + n0 + 32 + l31] = v1;
        }
    }
}

// ---- MFMA flash attention: barrier-free chunk loop, 2-wave key split, ------
// pi-permuted K (no P shuffles), K register-prefetch one iteration ahead.
// Block = 128 threads = 2 waves on the SAME 32-row q-strip of one (b,h);
// wave w does chunks c = w, w+2, ... (exp2-domain softmax: partials over
// disjoint chunk sets are additive -- validated R2-R12). All 4096 waves
// co-resident (R12's 4-wave split broke residency: 32 waves/CU needed vs
// 20 cap -> reverted). Per iteration: issue V(c) loads, then K(c+2) loads
// (stay in flight past V's vmcnt drain), compute S from pre-loaded K regs.
// With pi-permuted K, S^T C reg r at grp g = logical key
// s0 + ((r&8)<<1) + 8g + (r&7)  (st1: +32); PV A-frag kkp = straight pack of
// regs 8*(kkp&1)..+7 of p0 (kkp<2) or p1. One final __syncthreads combine.
// Qb bf16 [b*2048+t][h*64+d] pre-scaled by 0.125*log2e.
// O stored bf16 in GEMM A-tiled layout for the O-projection.
__global__ __launch_bounds__(128) void flash_attn(
        const unsigned short* __restrict__ Qb, const unsigned short* __restrict__ Ktl,
        const unsigned short* __restrict__ Vtl, unsigned short* __restrict__ Ot) {
    __shared__ float sO[64][33];                // wave1 partial O (padded)
    __shared__ float sL[64];                    // wave1 partial l
    const int tid = threadIdx.x;
    const int lane = tid & 63, w = tid >> 6;    // w: 0..1 (key-split)
    const int ln = lane & 31, grp = lane >> 5;
    const int id = blockIdx.x;                  // 0..2047
    const int kvh = id & 3;
    const int b = (id >> 2) & 1;
    const int h = kvh * 4 + ((id >> 3) & 3);
    const int strip = 63 - (id >> 5);           // heavy strips first
    const int t0w = strip * 32;
    const int qrow_g = t0w + ln;
    const int nch = (strip >> 1) + 1;           // causal 64-key chunks

    // Q B-frags in registers (read once): qf[kk] holds d = kk*16 + grp*8 + j
    const unsigned short* Qrow = Qb + (size_t)(b * 2048 + qrow_g) * 1024 + h * 64;
    s16x8 qf[4];
#pragma unroll
    for (int kk = 0; kk < 4; ++kk)
        qf[kk] = *reinterpret_cast<const s16x8*>(Qrow + kk * 16 + grp * 8);

    // per-(b,kvh) chunk-tiled bases; lane offset (grp*64+ln)*8 within a frag row
    const unsigned short* Kc = Ktl + (size_t)((b * 4 + kvh) * 32) * 4096
                                   + ((size_t)grp * 64 + ln) * 8;
    const unsigned short* Vc = Vtl + (size_t)((b * 4 + kvh) * 32) * 4096
                                   + ((size_t)grp * 64 + ln) * 8;

    f32x16 o0 = {}, o1 = {};
    float ltot = 0.f;

    // preload K frags of this wave's first chunk
    s16x8 kf0[4], kf1[4];
    {
        const unsigned short* kc = Kc + (size_t)w * 4096;
#pragma unroll
        for (int kk = 0; kk < 4; ++kk) {
            kf0[kk] = *reinterpret_cast<const s16x8*>(kc + kk * 1024);
            kf1[kk] = *reinterpret_cast<const s16x8*>(kc + kk * 1024 + 256);
        }
    }

    for (int c = w; c < nch; c += 2) {          // barrier-free, 2-way interleave
        const int s0 = c * 64;
        const unsigned short* vc = Vc + (size_t)c * 4096;
        // V loads first (drained before O-MFMAs) ...
        s16x8 vf0[4], vf1[4];
#pragma unroll
        for (int kk = 0; kk < 4; ++kk) {
            vf0[kk] = *reinterpret_cast<const s16x8*>(vc + kk * 1024);
            vf1[kk] = *reinterpret_cast<const s16x8*>(vc + kk * 1024 + 256);
        }
        // ... then next-iteration K loads (stay in flight past V's drain)
        const int cn = (c + 2 < nch) ? (c + 2) : c;
        const unsigned short* kn = Kc + (size_t)cn * 4096;
        s16x8 kn0[4], kn1[4];
#pragma unroll
        for (int kk = 0; kk < 4; ++kk) {
            kn0[kk] = *reinterpret_cast<const s16x8*>(kn + kk * 1024);
            kn1[kk] = *reinterpret_cast<const s16x8*>(kn + kk * 1024 + 256);
        }
        // ---- S^T = K Q^T from pre-loaded K regs ----
        f32x16 st0 = {}, st1 = {};
#pragma unroll
        for (int kk = 0; kk < 4; ++kk) {
            st0 = MFMA32(kf0[kk], qf[kk], st0);
            st1 = MFMA32(kf1[kk], qf[kk], st1);
        }
        if (s0 + 63 > t0w) {                   // diagonal chunk: causal mask (logical keys)
#pragma unroll
            for (int r = 0; r < 16; ++r) {
                const int keyo = s0 + ((r & 8) << 1) + 8 * grp + (r & 7);
                if (keyo > qrow_g)      st0[r] = -INFINITY;
                if (keyo + 32 > qrow_g) st1[r] = -INFINITY;
            }
        }
        // ---- P = exp2(S^T); all 32 values belong to qrow = ln ----
        f32x16 p0, p1;
#pragma unroll
        for (int r = 0; r < 16; ++r) {
            p0[r] = __builtin_amdgcn_exp2f(st0[r]);
            p1[r] = __builtin_amdgcn_exp2f(st1[r]);
        }
        float a0 = 0.f, a1 = 0.f, a2 = 0.f, a3 = 0.f;
#pragma unroll
        for (int r = 0; r < 16; r += 2) {
            a0 += p0[r]; a1 += p0[r + 1];
            a2 += p1[r]; a3 += p1[r + 1];
        }
        ltot += (a0 + a1) + (a2 + a3);
        // ---- P A-frags: straight in-lane packs (pi cancels the C scramble) ----
#pragma unroll
        for (int kkp = 0; kkp < 4; ++kkp) {
            const f32x16& pm = (kkp < 2) ? p0 : p1;
            const int base = 8 * (kkp & 1);
            union { unsigned int u[4]; s16x8 v; } pf;
            pf.u[0] = pktr(pm[base + 0], pm[base + 1]);
            pf.u[1] = pktr(pm[base + 2], pm[base + 3]);
            pf.u[2] = pktr(pm[base + 4], pm[base + 5]);
            pf.u[3] = pktr(pm[base + 6], pm[base + 7]);
            o0 = MFMA32(pf.v, vf0[kkp], o0);
            o1 = MFMA32(pf.v, vf1[kkp], o1);
        }
        // rotate prefetched K into place
#pragma unroll
        for (int kk = 0; kk < 4; ++kk) {
            kf0[kk] = kn0[kk];
            kf1[kk] = kn1[kk];
        }
    }

    // ---- combine wave 1 partials into wave 0 (single barrier) ----
    if (w == 1) {
#pragma unroll
        for (int r = 0; r < 16; ++r) {
            sO[lane][r] = o0[r];
            sO[lane][16 + r] = o1[r];
        }
        sL[lane] = ltot;
    }
    __syncthreads();
    if (w == 1) return;
#pragma unroll
    for (int r = 0; r < 16; ++r) {
        o0[r] += sO[lane][r];
        o1[r] += sO[lane][16 + r];
    }
    ltot += sL[lane];

    // ---- normalize + store bf16 in GEMM A-tiled layout ----
    const float lfull = ltot + __shfl_xor(ltot, 32, 64);
    const float rl = 1.0f / lfull;             // valid at every lane for row=ln
    unsigned short* Otb = Ot + (size_t)((b * 16 + (strip >> 2)) * 16 + h) * 8192
                             + (size_t)(ln >> 3) * 1024 + (ln & 7);
#pragma unroll
    for (int r = 0; r < 16; ++r) {
        const int row = (r & 3) + 8 * (r >> 2) + 4 * grp;
        const float rr = __shfl(rl, row, 64);
        const size_t off = (size_t)((strip & 3) * 32 + row) * 8;
        Otb[off]        = f2bf(o0[r] * rr);    // d-tile 0 (cols h*64+0..31)
        Otb[off + 4096] = f2bf(o1[r] * rr);    // d-tile 1 (cols h*64+32..63)
    }
}

// ---------------------------------------------------------------------------
extern "C" void kernel_launch(void* const* d_in, const int* in_sizes, int n_in,
                              void* d_out, int out_size, void* d_ws, size_t ws_size,
                              hipStream_t stream) {
    const float* x  = (const float*)d_in[0];
    // d_in[1] = causal mask, analytic -> ignored
    const float* Wq = (const float*)d_in[2];
    const float* bq = (const float*)d_in[3];
    const float* Wk = (const float*)d_in[4];
    const float* bk = (const float*)d_in[5];
    const float* Wv = (const float*)d_in[6];
    const float* bv = (const float*)d_in[7];
    const float* Wo = (const float*)d_in[8];
    const float* bo = (const float*)d_in[9];
    float* out = (float*)d_out;

    char* ws = (char*)d_ws;
    unsigned short* xb    = (unsigned short*)(ws);                  // 8 MB  A-tiled bf16 x
    unsigned short* Wqkv  = (unsigned short*)(ws + (8u  << 20));    // 3 MB  B-tiled concat W^T
    unsigned short* Wot   = (unsigned short*)(ws + (12u << 20));    // 2 MB  B-tiled Wo^T
    float*          biasq = (float*)         (ws + (15u << 20));    // 6 KB
    unsigned short* Qb    = (unsigned short*)(ws + (16u << 20));    // 8 MB
    unsigned short* Ktl   = (unsigned short*)(ws + (24u << 20));    // 2 MB chunk-tiled K (pi-permuted)
    unsigned short* Vtl   = (unsigned short*)(ws + (26u << 20));    // 2 MB chunk-tiled V^T
    unsigned short* Otl   = (unsigned short*)(ws + (28u << 20));    // 8 MB A-tiled (ends 36 MB)

    const float qscale = 0.125f * 1.4426950408889634f;  // 1/sqrt(64) * log2(e)

    prep<<<3078, 256, 0, stream>>>(x, Wq, Wk, Wv, Wo, bq, bk, bv,
                                   xb, Wqkv, Wot, biasq, qscale);
    gemm_mn<0><<<dim3(24, 32), 256, 0, stream>>>(xb, Wqkv, biasq, Qb, Ktl, Vtl, nullptr);
    flash_attn<<<2048, 128, 0, stream>>>(Qb, Ktl, Vtl, Otl);
    gemm_mn<1><<<dim3(16, 32), 256, 0, stream>>>(Otl, Wot, bo, nullptr, nullptr, nullptr, out);
}